// Round 5
// baseline (3962.702 us; speedup 1.0000x reference)
//
#include <hip/hip_runtime.h>
#include <stdint.h>
#include <math.h>

// Problem constants (B, H, T) = (16, 2048, 512)
#define Hdim   2048
#define Bdim   16
#define Tsteps 512
#define NWG    128   // workgroups; each owns KC columns of h
#define TPB    256   // 4 waves
#define KC     16    // h-columns per WG  (NWG*KC == Hdim)
#define NCHUNK 16    // K-chunks of 32 per wave (wave K-range = 512)
#define NFLAGS (NWG * 4)   // one flag per wave, grouped by producer group

typedef __attribute__((ext_vector_type(8))) short short8_t;  // 8 bf16 (4 VGPRs)
typedef __attribute__((ext_vector_type(4))) float f32x4;     // MFMA C/D

__device__ __forceinline__ short f2bf(float x) {
  uint32_t u = __builtin_bit_cast(uint32_t, x);
  u += 0x7fffu + ((u >> 16) & 1u);   // RNE
  return (short)(u >> 16);
}

__device__ __forceinline__ short8_t load8_bf(const float* __restrict__ p) {
  short8_t r;
#pragma unroll
  for (int j = 0; j < 8; ++j) r[j] = f2bf(p[j]);
  return r;
}

// Wait until all 64 flags of producer group g reach `want`.
// flags are contiguous: group g = flags[64g .. 64g+64) (two 128B lines).
__device__ __forceinline__ void poll_group(const uint32_t* __restrict__ flags,
                                           int g, int lane, uint32_t want) {
  const uint32_t* p = flags + g * 64 + lane;
  bool mine = false;
  for (;;) {
    if (!mine)
      mine = (__hip_atomic_load(p, __ATOMIC_RELAXED, __HIP_MEMORY_SCOPE_AGENT) >= want);
    if (__ballot(!mine) == 0ull) break;   // all 64 flags satisfied
    __builtin_amdgcn_s_sleep(1);
  }
}

__global__ void __launch_bounds__(TPB, 1) traj_kernel(
    const float* __restrict__ traj_z, const float* __restrict__ traj_input,
    const float* __restrict__ w_ih, const float* __restrict__ b_ih,
    const float* __restrict__ w_hh, const float* __restrict__ b_hh,
    const float* __restrict__ w_traj, const float* __restrict__ b_traj,
    float* __restrict__ out, uint32_t* __restrict__ hbuf32, uint32_t* __restrict__ flags)
{
  const int tid  = threadIdx.x;
  const int wg   = blockIdx.x;
  const int wave = tid >> 6;
  const int lane = tid & 63;
  const int ln16 = lane & 15;       // MFMA: A row (batch) / B col / D col
  const int quad = lane >> 4;
  const int colbase = wg * KC;
  const int kwave   = wave * (Hdim / 4);   // this wave's K-quarter
  const int myflag  = wg * 4 + wave;       // contiguous within producer group wg>>4

  uint64_t* hbuf64 = (uint64_t*)hbuf32;

  __shared__ float s_red[2][4][3][16][16];  // parity, wave, gate-tile, m, n = 24 KB
  __shared__ float s_x3[2][4][16];          // parity, wave, batch

  // ---- preload w_hh slice as register-resident bf16 B-fragments ----
  // B[k][n]: n = lane&15 (tile row), k = quad*8 + j within each 32-chunk.
  short8_t wf0[NCHUNK], wf1[NCHUNK], wf2[NCHUNK], wt[NCHUNK];
#pragma unroll
  for (int c = 0; c < NCHUNK; ++c) {
    const int k0 = kwave + c * 32 + quad * 8;
    wf0[c] = load8_bf(w_hh + (size_t)(0 * Hdim + colbase + ln16) * Hdim + k0);
    wf1[c] = load8_bf(w_hh + (size_t)(1 * Hdim + colbase + ln16) * Hdim + k0);
    wf2[c] = load8_bf(w_hh + (size_t)(2 * Hdim + colbase + ln16) * Hdim + k0);
    short8_t g = {0, 0, 0, 0, 0, 0, 0, 0};
    if (ln16 == 0) g = load8_bf(w_traj + k0);
    wt[c] = g;
  }

  // ---- per-thread epilogue constants: thread (eb, ekc) owns h[eb][colbase+ekc] ----
  const int eb   = tid >> 4;
  const int ekc  = tid & 15;
  const int ecol = colbase + ekc;
  const float wr = w_ih[ecol], wz = w_ih[Hdim + ecol], wn = w_ih[2 * Hdim + ecol];
  const float br = b_ih[ecol] + b_hh[ecol];
  const float bz = b_ih[Hdim + ecol] + b_hh[Hdim + ecol];
  const float bin = b_ih[2 * Hdim + ecol];
  const float bhn = b_hh[2 * Hdim + ecol];
  const float bt  = b_traj[0];
  float h_own = traj_z[eb * Hdim + ecol];
  float x_run = traj_input[eb * Tsteps];   // running x (identical across threads w/ same eb)

  // ---- publish h_0: per-wave store + own drain + own flag (no WG barrier) ----
  {
    uint32_t mybits = (uint32_t)(uint16_t)f2bf(h_own);
    uint32_t nb = (uint32_t)__shfl_xor((int)mybits, 1, 64);
    if ((tid & 1) == 0) {
      uint32_t packed = (mybits & 0xffffu) | (nb << 16);
      __hip_atomic_store(hbuf32 + ((eb * Hdim + ecol) >> 1),
                         packed, __ATOMIC_RELAXED, __HIP_MEMORY_SCOPE_AGENT);
    }
    asm volatile("s_waitcnt vmcnt(0)" ::: "memory");   // this wave's h_0 acked
    if (lane == 0)
      __hip_atomic_store(flags + myflag, 1u, __ATOMIC_RELAXED, __HIP_MEMORY_SCOPE_AGENT);
  }

  // step i: polls h_i groups incrementally, computes h_{i+1} and x_i;
  // out[:, i-1] = x_i. Extra iteration i==Tsteps computes only x_T.
  for (int i = 0; i <= Tsteps; ++i) {
    const uint32_t want = (uint32_t)(i + 1);
    const int par = i & 1;
    const uint64_t* hrow = hbuf64 + (size_t)par * (Bdim * Hdim / 4)
                         + ((ln16 * Hdim + kwave + quad * 8) >> 2);

    union { uint64_t u[2]; short8_t s; } cv[NCHUNK];

    // group 2*wave covers chunks 0..7; issue loads, then poll next group to hide latency
    poll_group(flags, 2 * wave, lane, want);
#pragma unroll
    for (int c = 0; c < 8; ++c) {
      cv[c].u[0] = __hip_atomic_load(hrow + c * 8,     __ATOMIC_RELAXED, __HIP_MEMORY_SCOPE_AGENT);
      cv[c].u[1] = __hip_atomic_load(hrow + c * 8 + 1, __ATOMIC_RELAXED, __HIP_MEMORY_SCOPE_AGENT);
    }
    poll_group(flags, 2 * wave + 1, lane, want);
#pragma unroll
    for (int c = 8; c < NCHUNK; ++c) {
      cv[c].u[0] = __hip_atomic_load(hrow + c * 8,     __ATOMIC_RELAXED, __HIP_MEMORY_SCOPE_AGENT);
      cv[c].u[1] = __hip_atomic_load(hrow + c * 8 + 1, __ATOMIC_RELAXED, __HIP_MEMORY_SCOPE_AGENT);
    }

    f32x4 a0 = {0.f, 0.f, 0.f, 0.f}, a1 = a0, a2 = a0, a3 = a0;
#pragma unroll
    for (int c = 0; c < NCHUNK; ++c) {
      a0 = __builtin_amdgcn_mfma_f32_16x16x32_bf16(cv[c].s, wf0[c], a0, 0, 0, 0);
      a1 = __builtin_amdgcn_mfma_f32_16x16x32_bf16(cv[c].s, wf1[c], a1, 0, 0, 0);
      a2 = __builtin_amdgcn_mfma_f32_16x16x32_bf16(cv[c].s, wf2[c], a2, 0, 0, 0);
      a3 = __builtin_amdgcn_mfma_f32_16x16x32_bf16(cv[c].s, wt[c],  a3, 0, 0, 0);
    }

    // D[m][n]: n = lane&15, m = quad*4 + r
#pragma unroll
    for (int r = 0; r < 4; ++r) {
      const int m = quad * 4 + r;
      s_red[par][wave][0][m][ln16] = a0[r];
      s_red[par][wave][1][m][ln16] = a1[r];
      s_red[par][wave][2][m][ln16] = a2[r];
    }
    if (ln16 == 0) {
#pragma unroll
      for (int r = 0; r < 4; ++r) s_x3[par][wave][quad * 4 + r] = a3[r];
    }
    __syncthreads();   // the ONLY barrier per step (parity buffers handle reuse)

    // x_i = x_{i-1} + dot(h_i, w_traj) + b_traj  (register-held, per-thread)
    if (i > 0)
      x_run += s_x3[par][0][eb] + s_x3[par][1][eb] + s_x3[par][2][eb] + s_x3[par][3][eb] + bt;
    if (i == Tsteps) {
      if (wg == 0 && ekc == 0) out[eb * Tsteps + (i - 1)] = x_run;
      break;
    }

    // gates for (eb, ecol)
    const float gr = s_red[par][0][0][eb][ekc] + s_red[par][1][0][eb][ekc] + s_red[par][2][0][eb][ekc] + s_red[par][3][0][eb][ekc];
    const float gz = s_red[par][0][1][eb][ekc] + s_red[par][1][1][eb][ekc] + s_red[par][2][1][eb][ekc] + s_red[par][3][1][eb][ekc];
    const float gn = s_red[par][0][2][eb][ekc] + s_red[par][1][2][eb][ekc] + s_red[par][2][2][eb][ekc] + s_red[par][3][2][eb][ekc];
    const float rr = 1.f / (1.f + expf(-(x_run * wr + br + gr)));
    const float zz = 1.f / (1.f + expf(-(x_run * wz + bz + gz)));
    const float nn = tanhf(x_run * wn + bin + rr * (gn + bhn));
    h_own = (1.f - zz) * nn + zz * h_own;

    // publish h_{i+1}: per-wave store + own drain + own flag
    {
      uint32_t mybits = (uint32_t)(uint16_t)f2bf(h_own);
      uint32_t nb = (uint32_t)__shfl_xor((int)mybits, 1, 64);
      if ((tid & 1) == 0) {
        uint32_t packed = (mybits & 0xffffu) | (nb << 16);
        __hip_atomic_store(hbuf32 + (size_t)((i + 1) & 1) * (Bdim * Hdim / 2)
                           + ((eb * Hdim + ecol) >> 1),
                           packed, __ATOMIC_RELAXED, __HIP_MEMORY_SCOPE_AGENT);
      }
      asm volatile("s_waitcnt vmcnt(0)" ::: "memory");
      if (lane == 0)
        __hip_atomic_store(flags + myflag, (uint32_t)(i + 2),
                           __ATOMIC_RELAXED, __HIP_MEMORY_SCOPE_AGENT);
    }

    // out store AFTER publish: keeps wg0's drain off the chip-wide critical path
    if (wg == 0 && ekc == 0 && i > 0) out[eb * Tsteps + (i - 1)] = x_run;
  }
}

extern "C" void kernel_launch(void* const* d_in, const int* in_sizes, int n_in,
                              void* d_out, int out_size, void* d_ws, size_t ws_size,
                              hipStream_t stream) {
  const float* traj_z     = (const float*)d_in[0];
  const float* traj_input = (const float*)d_in[1];
  const float* w_ih   = (const float*)d_in[2];
  const float* b_ih   = (const float*)d_in[3];
  const float* w_hh   = (const float*)d_in[4];
  const float* b_hh   = (const float*)d_in[5];
  const float* w_traj = (const float*)d_in[6];
  const float* b_traj = (const float*)d_in[7];
  float* out = (float*)d_out;

  uint8_t*  ws    = (uint8_t*)d_ws;
  uint32_t* flags = (uint32_t*)ws;             // 512 flags = 2 KB (16 lines)
  uint32_t* hbuf  = (uint32_t*)(ws + 4096);    // 2 * 16 * 2048 bf16 = 128 KB

  (void)hipMemsetAsync(flags, 0, NFLAGS * 4, stream);  // flags must start at 0
  hipLaunchKernelGGL(traj_kernel, dim3(NWG), dim3(TPB), 0, stream,
                     traj_z, traj_input, w_ih, b_ih, w_hh, b_hh, w_traj, b_traj,
                     out, hbuf, flags);
}

// Round 6
// 3934.372 us; speedup vs baseline: 1.0072x; 1.0072x over previous
//
#include <hip/hip_runtime.h>
#include <stdint.h>
#include <math.h>

// Problem constants (B, H, T) = (16, 2048, 512)
#define Hdim   2048
#define Bdim   16
#define Tsteps 512
#define NWG    128   // workgroups; each owns KC columns of h
#define TPB    256   // 4 waves
#define KC     16    // h-columns per WG  (NWG*KC == Hdim)
#define NCHUNK 16    // K-chunks of 32 per wave (wave K-range = 512)
#define NFLAGS (NWG * 4)   // one flag per wave, contiguous: flag = wg*4 + wave

typedef __attribute__((ext_vector_type(8))) short short8_t;  // 8 bf16 (4 VGPRs)
typedef __attribute__((ext_vector_type(4))) float f32x4;     // MFMA C/D

__device__ __forceinline__ short f2bf(float x) {
  uint32_t u = __builtin_bit_cast(uint32_t, x);
  u += 0x7fffu + ((u >> 16) & 1u);   // RNE
  return (short)(u >> 16);
}

__device__ __forceinline__ short8_t load8_bf(const float* __restrict__ p) {
  short8_t r;
#pragma unroll
  for (int j = 0; j < 8; ++j) r[j] = f2bf(p[j]);
  return r;
}

__device__ __forceinline__ float rcp_f(float x) { return __builtin_amdgcn_rcpf(x); }

// Wave-scoped wait: flags[128w .. 128w+128) >= want  (2 contiguous loads/lane).
// These are exactly the 32 producer WGs (x4 waves) of wave w's K-quarter.
// NOTE: never interleave this with bulk data loads — vmcnt is in-order (R5 lesson).
__device__ __forceinline__ void poll_wave(const uint32_t* __restrict__ flags,
                                          int wave, int lane, uint32_t want) {
  const uint32_t* p = flags + wave * 128 + lane;
  bool ok0 = false, ok1 = false;
  for (;;) {
    uint32_t a = ok0 ? want : __hip_atomic_load(p,      __ATOMIC_RELAXED, __HIP_MEMORY_SCOPE_AGENT);
    uint32_t b = ok1 ? want : __hip_atomic_load(p + 64, __ATOMIC_RELAXED, __HIP_MEMORY_SCOPE_AGENT);
    ok0 = ok0 | (a >= want);
    ok1 = ok1 | (b >= want);
    if (__ballot(!(ok0 && ok1)) == 0ull) break;
    __builtin_amdgcn_s_sleep(1);
  }
}

__global__ void __launch_bounds__(TPB, 1) traj_kernel(
    const float* __restrict__ traj_z, const float* __restrict__ traj_input,
    const float* __restrict__ w_ih, const float* __restrict__ b_ih,
    const float* __restrict__ w_hh, const float* __restrict__ b_hh,
    const float* __restrict__ w_traj, const float* __restrict__ b_traj,
    float* __restrict__ out, uint32_t* __restrict__ hbuf32, uint32_t* __restrict__ flags)
{
  const int tid  = threadIdx.x;
  const int wg   = blockIdx.x;
  const int wave = tid >> 6;
  const int lane = tid & 63;
  const int ln16 = lane & 15;       // MFMA: A row (batch) / B col / D col
  const int quad = lane >> 4;
  const int colbase = wg * KC;
  const int kwave   = wave * (Hdim / 4);   // this wave's K-quarter
  const int myflag  = wg * 4 + wave;

  uint64_t* hbuf64 = (uint64_t*)hbuf32;

  __shared__ float s_red[2][4][3][16][16];  // parity, wave, gate, m, n = 24 KB
  __shared__ float s_x3[2][4][16];          // parity, wave, batch

  // ---- preload w_hh slice as register-resident bf16 B-fragments ----
  // B[k][n]: n = lane&15 (tile row), k = quad*8 + j within each 32-chunk.
  short8_t wf0[NCHUNK], wf1[NCHUNK], wf2[NCHUNK], wt[NCHUNK];
#pragma unroll
  for (int c = 0; c < NCHUNK; ++c) {
    const int k0 = kwave + c * 32 + quad * 8;
    wf0[c] = load8_bf(w_hh + (size_t)(0 * Hdim + colbase + ln16) * Hdim + k0);
    wf1[c] = load8_bf(w_hh + (size_t)(1 * Hdim + colbase + ln16) * Hdim + k0);
    wf2[c] = load8_bf(w_hh + (size_t)(2 * Hdim + colbase + ln16) * Hdim + k0);
    short8_t g = {0, 0, 0, 0, 0, 0, 0, 0};
    if (ln16 == 0) g = load8_bf(w_traj + k0);
    wt[c] = g;
  }

  // ---- per-thread epilogue constants: thread (eb, ekc) owns h[eb][colbase+ekc] ----
  const int eb   = tid >> 4;
  const int ekc  = tid & 15;
  const int ecol = colbase + ekc;
  const float wr = w_ih[ecol], wz = w_ih[Hdim + ecol], wn = w_ih[2 * Hdim + ecol];
  const float br = b_ih[ecol] + b_hh[ecol];
  const float bz = b_ih[Hdim + ecol] + b_hh[Hdim + ecol];
  const float bin = b_ih[2 * Hdim + ecol];
  const float bhn = b_hh[2 * Hdim + ecol];
  const float bt  = b_traj[0];
  float h_own = traj_z[eb * Hdim + ecol];
  float x_run = traj_input[eb * Tsteps];   // running x (identical across threads w/ same eb)

  // ---- publish h_0: per-wave store + own drain + own flag ----
  {
    uint32_t mybits = (uint32_t)(uint16_t)f2bf(h_own);
    uint32_t nb = (uint32_t)__shfl_xor((int)mybits, 1, 64);
    if ((tid & 1) == 0) {
      uint32_t packed = (mybits & 0xffffu) | (nb << 16);
      __hip_atomic_store(hbuf32 + ((eb * Hdim + ecol) >> 1),
                         packed, __ATOMIC_RELAXED, __HIP_MEMORY_SCOPE_AGENT);
    }
    asm volatile("s_waitcnt vmcnt(0)" ::: "memory");
    if (lane == 0)
      __hip_atomic_store(flags + myflag, 1u, __ATOMIC_RELAXED, __HIP_MEMORY_SCOPE_AGENT);
  }

  // step i: wave-scoped poll of h_i producers, full load, MFMA; one barrier/step.
  // out[:, i-1] = x_i. Extra iteration i==Tsteps computes only x_T.
  for (int i = 0; i <= Tsteps; ++i) {
    const uint32_t want = (uint32_t)(i + 1);
    const int par = i & 1;
    const uint64_t* hrow = hbuf64 + (size_t)par * (Bdim * Hdim / 4)
                         + ((ln16 * Hdim + kwave + quad * 8) >> 2);

    // 1) poll fully (this wave's producers only) — no data loads in flight
    poll_wave(flags, wave, lane, want);

    // 2) then issue ALL data loads back-to-back
    union { uint64_t u[2]; short8_t s; } cv[NCHUNK];
#pragma unroll
    for (int c = 0; c < NCHUNK; ++c) {
      cv[c].u[0] = __hip_atomic_load(hrow + c * 8,     __ATOMIC_RELAXED, __HIP_MEMORY_SCOPE_AGENT);
      cv[c].u[1] = __hip_atomic_load(hrow + c * 8 + 1, __ATOMIC_RELAXED, __HIP_MEMORY_SCOPE_AGENT);
    }

    f32x4 a0 = {0.f, 0.f, 0.f, 0.f}, a1 = a0, a2 = a0, a3 = a0;
#pragma unroll
    for (int c = 0; c < NCHUNK; ++c) {
      a0 = __builtin_amdgcn_mfma_f32_16x16x32_bf16(cv[c].s, wf0[c], a0, 0, 0, 0);
      a1 = __builtin_amdgcn_mfma_f32_16x16x32_bf16(cv[c].s, wf1[c], a1, 0, 0, 0);
      a2 = __builtin_amdgcn_mfma_f32_16x16x32_bf16(cv[c].s, wf2[c], a2, 0, 0, 0);
      a3 = __builtin_amdgcn_mfma_f32_16x16x32_bf16(cv[c].s, wt[c],  a3, 0, 0, 0);
    }

    // D[m][n]: n = lane&15, m = quad*4 + r
#pragma unroll
    for (int r = 0; r < 4; ++r) {
      const int m = quad * 4 + r;
      s_red[par][wave][0][m][ln16] = a0[r];
      s_red[par][wave][1][m][ln16] = a1[r];
      s_red[par][wave][2][m][ln16] = a2[r];
    }
    if (ln16 == 0) {
#pragma unroll
      for (int r = 0; r < 4; ++r) s_x3[par][wave][quad * 4 + r] = a3[r];
    }
    __syncthreads();   // the ONLY barrier per step (parity buffers handle reuse);
                       // also completes the WG's collective poll of ALL 512 flags
                       // => everyone finished reading h_{i-1} => safe to overwrite below.

    // x_i = x_{i-1} + dot(h_i, w_traj) + b_traj  (register-held, per-thread)
    if (i > 0)
      x_run += s_x3[par][0][eb] + s_x3[par][1][eb] + s_x3[par][2][eb] + s_x3[par][3][eb] + bt;
    if (i == Tsteps) {
      if (wg == 0 && ekc == 0) out[eb * Tsteps + (i - 1)] = x_run;
      break;
    }

    // gates for (eb, ecol) — fast transcendentals (v_exp + v_rcp)
    const float gr = s_red[par][0][0][eb][ekc] + s_red[par][1][0][eb][ekc] + s_red[par][2][0][eb][ekc] + s_red[par][3][0][eb][ekc];
    const float gz = s_red[par][0][1][eb][ekc] + s_red[par][1][1][eb][ekc] + s_red[par][2][1][eb][ekc] + s_red[par][3][1][eb][ekc];
    const float gn = s_red[par][0][2][eb][ekc] + s_red[par][1][2][eb][ekc] + s_red[par][2][2][eb][ekc] + s_red[par][3][2][eb][ekc];
    const float rr = rcp_f(1.f + __expf(-(x_run * wr + br + gr)));
    const float zz = rcp_f(1.f + __expf(-(x_run * wz + bz + gz)));
    const float e2 = __expf(2.f * (x_run * wn + bin + rr * (gn + bhn)));
    const float nn = 1.f - 2.f * rcp_f(e2 + 1.f);     // tanh
    h_own = (1.f - zz) * nn + zz * h_own;

    // publish h_{i+1}: per-wave store + own drain + own flag
    {
      uint32_t mybits = (uint32_t)(uint16_t)f2bf(h_own);
      uint32_t nb = (uint32_t)__shfl_xor((int)mybits, 1, 64);
      if ((tid & 1) == 0) {
        uint32_t packed = (mybits & 0xffffu) | (nb << 16);
        __hip_atomic_store(hbuf32 + (size_t)((i + 1) & 1) * (Bdim * Hdim / 2)
                           + ((eb * Hdim + ecol) >> 1),
                           packed, __ATOMIC_RELAXED, __HIP_MEMORY_SCOPE_AGENT);
      }
      asm volatile("s_waitcnt vmcnt(0)" ::: "memory");
      if (lane == 0)
        __hip_atomic_store(flags + myflag, (uint32_t)(i + 2),
                           __ATOMIC_RELAXED, __HIP_MEMORY_SCOPE_AGENT);
    }

    // out store AFTER publish: keeps wg0's drain off the chip-wide critical path
    if (wg == 0 && ekc == 0 && i > 0) out[eb * Tsteps + (i - 1)] = x_run;
  }
}

extern "C" void kernel_launch(void* const* d_in, const int* in_sizes, int n_in,
                              void* d_out, int out_size, void* d_ws, size_t ws_size,
                              hipStream_t stream) {
  const float* traj_z     = (const float*)d_in[0];
  const float* traj_input = (const float*)d_in[1];
  const float* w_ih   = (const float*)d_in[2];
  const float* b_ih   = (const float*)d_in[3];
  const float* w_hh   = (const float*)d_in[4];
  const float* b_hh   = (const float*)d_in[5];
  const float* w_traj = (const float*)d_in[6];
  const float* b_traj = (const float*)d_in[7];
  float* out = (float*)d_out;

  uint8_t*  ws    = (uint8_t*)d_ws;
  uint32_t* flags = (uint32_t*)ws;             // 512 contiguous flags = 2 KB
  uint32_t* hbuf  = (uint32_t*)(ws + 4096);    // 2 * 16 * 2048 bf16 = 128 KB

  (void)hipMemsetAsync(flags, 0, NFLAGS * 4, stream);  // flags must start at 0
  hipLaunchKernelGGL(traj_kernel, dim3(NWG), dim3(TPB), 0, stream,
                     traj_z, traj_input, w_ih, b_ih, w_hh, b_hh, w_traj, b_traj,
                     out, hbuf, flags);
}

// Round 7
// 3060.207 us; speedup vs baseline: 1.2949x; 1.2857x over previous
//
#include <hip/hip_runtime.h>
#include <stdint.h>
#include <math.h>

// Problem constants (B, H, T) = (16, 2048, 512)
#define Hdim   2048
#define Bdim   16
#define Tsteps 512
#define NWG    128   // workgroups; each owns KC columns of h
#define TPB    256   // 4 waves
#define KC     16    // h-columns per WG  (NWG*KC == Hdim)
#define NCHUNK 16    // K-chunks of 32 per wave (wave K-range = 512)
#define FLAGSTRIDE 32  // uint32s between per-WG flags (128B: ONE WRITER PER LINE)

typedef __attribute__((ext_vector_type(8))) short short8_t;  // 8 bf16 (4 VGPRs)
typedef __attribute__((ext_vector_type(4))) float f32x4;     // MFMA C/D

__device__ __forceinline__ short f2bf(float x) {
  uint32_t u = __builtin_bit_cast(uint32_t, x);
  u += 0x7fffu + ((u >> 16) & 1u);   // RNE
  return (short)(u >> 16);
}

__device__ __forceinline__ short8_t load8_bf(const float* __restrict__ p) {
  short8_t r;
#pragma unroll
  for (int j = 0; j < 8; ++j) r[j] = f2bf(p[j]);
  return r;
}

__device__ __forceinline__ float rcp_f(float x) { return __builtin_amdgcn_rcpf(x); }

// publish: drain this WG's h-stores (explicit vmcnt(0) + the one __syncthreads
// emits), then ONE thread stores this WG's flag into its PRIVATE 128B line.
__device__ __forceinline__ void publish(uint32_t* flags, int wg, int tid, uint32_t n) {
  asm volatile("s_waitcnt vmcnt(0)" ::: "memory");
  __syncthreads();
  if (tid == 0)
    __hip_atomic_store(flags + wg * FLAGSTRIDE, n, __ATOMIC_RELAXED, __HIP_MEMORY_SCOPE_AGENT);
}
// waitall: thread t (<NWG) polls WG t's flag (its own line) until it reaches n.
__device__ __forceinline__ void waitall(const uint32_t* flags, int tid, uint32_t n) {
  if (tid < NWG) {
    while (__hip_atomic_load(flags + tid * FLAGSTRIDE, __ATOMIC_RELAXED,
                             __HIP_MEMORY_SCOPE_AGENT) < n) {
      __builtin_amdgcn_s_sleep(1);
    }
  }
  __syncthreads();
}

__global__ void __launch_bounds__(TPB, 1) traj_kernel(
    const float* __restrict__ traj_z, const float* __restrict__ traj_input,
    const float* __restrict__ w_ih, const float* __restrict__ b_ih,
    const float* __restrict__ w_hh, const float* __restrict__ b_hh,
    const float* __restrict__ w_traj, const float* __restrict__ b_traj,
    float* __restrict__ out, uint32_t* __restrict__ hbuf32, uint32_t* __restrict__ flags)
{
  const int tid  = threadIdx.x;
  const int wg   = blockIdx.x;
  const int wave = tid >> 6;
  const int lane = tid & 63;
  const int ln16 = lane & 15;       // MFMA: A row (batch) / B col / D col
  const int quad = lane >> 4;
  const int colbase = wg * KC;
  const int kwave   = wave * (Hdim / 4);   // this wave's K-quarter

  uint64_t* hbuf64 = (uint64_t*)hbuf32;

  __shared__ float s_red[4][3][16][16];  // wave, gate-tile, m(batch), n(col) = 12 KB
  __shared__ float s_x3[4][16];          // per-wave partial dot(h, w_traj)

  // ---- preload w_hh slice as register-resident bf16 B-fragments ----
  // B[k][n]: n = lane&15 (tile row), k = quad*8 + j within each 32-chunk.
  short8_t wf0[NCHUNK], wf1[NCHUNK], wf2[NCHUNK], wt[NCHUNK];
#pragma unroll
  for (int c = 0; c < NCHUNK; ++c) {
    const int k0 = kwave + c * 32 + quad * 8;
    wf0[c] = load8_bf(w_hh + (size_t)(0 * Hdim + colbase + ln16) * Hdim + k0);
    wf1[c] = load8_bf(w_hh + (size_t)(1 * Hdim + colbase + ln16) * Hdim + k0);
    wf2[c] = load8_bf(w_hh + (size_t)(2 * Hdim + colbase + ln16) * Hdim + k0);
    short8_t g = {0, 0, 0, 0, 0, 0, 0, 0};
    if (ln16 == 0) g = load8_bf(w_traj + k0);
    wt[c] = g;
  }

  // ---- per-thread epilogue constants: thread (eb, ekc) owns h[eb][colbase+ekc] ----
  const int eb   = tid >> 4;
  const int ekc  = tid & 15;
  const int ecol = colbase + ekc;
  const float wr = w_ih[ecol], wz = w_ih[Hdim + ecol], wn = w_ih[2 * Hdim + ecol];
  const float br = b_ih[ecol] + b_hh[ecol];
  const float bz = b_ih[Hdim + ecol] + b_hh[Hdim + ecol];
  const float bin = b_ih[2 * Hdim + ecol];
  const float bhn = b_hh[2 * Hdim + ecol];
  const float bt  = b_traj[0];
  float h_own = traj_z[eb * Hdim + ecol];
  float x_run = traj_input[eb * Tsteps];   // running x (identical across threads w/ same eb)

  // ---- publish h_0 (agent-scope stores; pack 2 bf16 per dword) ----
  {
    uint32_t mybits = (uint32_t)(uint16_t)f2bf(h_own);
    uint32_t nb = (uint32_t)__shfl_xor((int)mybits, 1, 64);
    if ((tid & 1) == 0) {
      uint32_t packed = (mybits & 0xffffu) | (nb << 16);
      __hip_atomic_store(hbuf32 + ((eb * Hdim + ecol) >> 1),
                         packed, __ATOMIC_RELAXED, __HIP_MEMORY_SCOPE_AGENT);
    }
  }
  publish(flags, wg, tid, 1);

  // step i: waits for h_i, computes h_{i+1} and x_i; out[:, i-1] = x_i.
  // Extra iteration i==Tsteps computes only x_T.
  for (int i = 0; i <= Tsteps; ++i) {
    waitall(flags, tid, (uint32_t)(i + 1));   // all WGs have published h_i

    // ---- load A-fragments of h_i (agent-scope, bypass stale L1/L2) ----
    const uint64_t* hrow = hbuf64 + (size_t)(i & 1) * (Bdim * Hdim / 4)
                         + ((ln16 * Hdim + kwave + quad * 8) >> 2);
    short8_t af[NCHUNK];
#pragma unroll
    for (int c = 0; c < NCHUNK; ++c) {
      union { uint64_t u[2]; short8_t s; } cv;
      cv.u[0] = __hip_atomic_load(hrow + c * 8,     __ATOMIC_RELAXED, __HIP_MEMORY_SCOPE_AGENT);
      cv.u[1] = __hip_atomic_load(hrow + c * 8 + 1, __ATOMIC_RELAXED, __HIP_MEMORY_SCOPE_AGENT);
      af[c] = cv.s;
    }

    f32x4 a0 = {0.f, 0.f, 0.f, 0.f}, a1 = a0, a2 = a0, a3 = a0;
#pragma unroll
    for (int c = 0; c < NCHUNK; ++c) {
      a0 = __builtin_amdgcn_mfma_f32_16x16x32_bf16(af[c], wf0[c], a0, 0, 0, 0);
      a1 = __builtin_amdgcn_mfma_f32_16x16x32_bf16(af[c], wf1[c], a1, 0, 0, 0);
      a2 = __builtin_amdgcn_mfma_f32_16x16x32_bf16(af[c], wf2[c], a2, 0, 0, 0);
      a3 = __builtin_amdgcn_mfma_f32_16x16x32_bf16(af[c], wt[c],  a3, 0, 0, 0);
    }

    // D[m][n]: n = lane&15, m = quad*4 + r
#pragma unroll
    for (int r = 0; r < 4; ++r) {
      const int m = quad * 4 + r;
      s_red[wave][0][m][ln16] = a0[r];
      s_red[wave][1][m][ln16] = a1[r];
      s_red[wave][2][m][ln16] = a2[r];
    }
    if (ln16 == 0) {
#pragma unroll
      for (int r = 0; r < 4; ++r) s_x3[wave][quad * 4 + r] = a3[r];
    }
    __syncthreads();   // s_red/s_x3 ready; reuse protected by publish+waitall barriers

    // x_i = x_{i-1} + dot(h_i, w_traj) + b_traj  (register-held)
    if (i > 0)
      x_run += s_x3[0][eb] + s_x3[1][eb] + s_x3[2][eb] + s_x3[3][eb] + bt;
    if (i == Tsteps) {
      if (wg == 0 && ekc == 0) out[eb * Tsteps + (i - 1)] = x_run;
      break;
    }

    // gates for (eb, ecol) — fast transcendentals (v_exp + v_rcp)
    const float gr = s_red[0][0][eb][ekc] + s_red[1][0][eb][ekc] + s_red[2][0][eb][ekc] + s_red[3][0][eb][ekc];
    const float gz = s_red[0][1][eb][ekc] + s_red[1][1][eb][ekc] + s_red[2][1][eb][ekc] + s_red[3][1][eb][ekc];
    const float gn = s_red[0][2][eb][ekc] + s_red[1][2][eb][ekc] + s_red[2][2][eb][ekc] + s_red[3][2][eb][ekc];
    const float rr = rcp_f(1.f + __expf(-(x_run * wr + br + gr)));
    const float zz = rcp_f(1.f + __expf(-(x_run * wz + bz + gz)));
    const float e2 = __expf(2.f * (x_run * wn + bin + rr * (gn + bhn)));
    const float nn = 1.f - 2.f * rcp_f(e2 + 1.f);     // tanh
    h_own = (1.f - zz) * nn + zz * h_own;

    // publish h_{i+1}
    {
      uint32_t mybits = (uint32_t)(uint16_t)f2bf(h_own);
      uint32_t nb = (uint32_t)__shfl_xor((int)mybits, 1, 64);
      if ((tid & 1) == 0) {
        uint32_t packed = (mybits & 0xffffu) | (nb << 16);
        __hip_atomic_store(hbuf32 + (size_t)((i + 1) & 1) * (Bdim * Hdim / 2)
                           + ((eb * Hdim + ecol) >> 1),
                           packed, __ATOMIC_RELAXED, __HIP_MEMORY_SCOPE_AGENT);
      }
    }
    publish(flags, wg, tid, (uint32_t)(i + 2));

    // out store AFTER publish: keeps wg0's store off the chip-wide critical path
    if (wg == 0 && ekc == 0 && i > 0) out[eb * Tsteps + (i - 1)] = x_run;
  }
}

extern "C" void kernel_launch(void* const* d_in, const int* in_sizes, int n_in,
                              void* d_out, int out_size, void* d_ws, size_t ws_size,
                              hipStream_t stream) {
  const float* traj_z     = (const float*)d_in[0];
  const float* traj_input = (const float*)d_in[1];
  const float* w_ih   = (const float*)d_in[2];
  const float* b_ih   = (const float*)d_in[3];
  const float* w_hh   = (const float*)d_in[4];
  const float* b_hh   = (const float*)d_in[5];
  const float* w_traj = (const float*)d_in[6];
  const float* b_traj = (const float*)d_in[7];
  float* out = (float*)d_out;

  uint8_t*  ws    = (uint8_t*)d_ws;
  uint32_t* flags = (uint32_t*)ws;                 // NWG*FLAGSTRIDE u32 = 16 KB
  uint32_t* hbuf  = (uint32_t*)(ws + NWG * FLAGSTRIDE * 4);  // 2*16*2048 bf16 = 128 KB

  (void)hipMemsetAsync(flags, 0, NWG * FLAGSTRIDE * 4, stream);
  hipLaunchKernelGGL(traj_kernel, dim3(NWG), dim3(TPB), 0, stream,
                     traj_z, traj_input, w_ih, b_ih, w_hh, b_hh, w_traj, b_traj,
                     out, hbuf, flags);
}